// Round 1
// baseline (7174.156 us; speedup 1.0000x reference)
//
#include <hip/hip_runtime.h>
#include <cstddef>

#define CIN 256
#define HW 49
#define XW_STRIDE 52   // padded row stride for [49]-float rows (16B aligned)
#define QK_STRIDE 68   // padded row stride for [64]-float rows (16B aligned)

// workspace layout (floats):
//      0 : WqkT  [256][512]
// 131072 : WvT   [256][256]
// 196608 : WprojT[256][256]
// 262144 : xc    [2048][256][49]
// total = 262144 + 25690112 floats = ~99 MB

__global__ void transpose256(const float* __restrict__ W, float* __restrict__ WT, int O) {
  int idx = blockIdx.x * 256 + threadIdx.x;
  if (idx >= O * 256) return;
  int o = idx >> 8, c = idx & 255;
  WT[c * O + o] = W[idx];
}

__global__ __launch_bounds__(256, 1) void win_attn(
    const float* __restrict__ x,
    const float* __restrict__ bn_g, const float* __restrict__ bn_b,
    const float* __restrict__ bn_m, const float* __restrict__ bn_v,
    const float* __restrict__ WqkT, const float* __restrict__ WvT,
    const float* __restrict__ w3, const float* __restrict__ w5,
    const float* __restrict__ w7,
    const float* __restrict__ aw, const float* __restrict__ c3w,
    const float* __restrict__ c5w, const float* __restrict__ c7w,
    float* __restrict__ xc_g)
{
  extern __shared__ float smem[];
  float* xw = smem;                     // [256][XW_STRIDE]
  float* vv = xw + 256 * XW_STRIDE;     // [256][XW_STRIDE]
  float* qh = vv + 256 * XW_STRIDE;     // [49][QK_STRIDE]
  float* kh = qh + HW * QK_STRIDE;      // [49][QK_STRIDE]
  float* Ss = kh + HW * QK_STRIDE;      // [49][XW_STRIDE]

  const int win = blockIdx.x;
  const int bb = win >> 6;
  const int i1 = (win >> 3) & 7;
  const int i2 = win & 7;
  const int tid = threadIdx.x;

  const float* xb = x + (size_t)bb * CIN * 3136 + i1 * 56 + i2;

  // ---- 1) load + BN into xw[c][p]  (p = h1*7+w1, global pixel (h1*8+i1, w1*8+i2))
  for (int t = tid; t < CIN * HW; t += 256) {
    int c = t / HW;
    int p = t - c * HW;
    int h1 = p / 7, w1 = p - (p / 7) * 7;
    float g = bn_g[c] * rsqrtf(bn_v[c] + 1e-5f);
    float val = xb[(size_t)c * 3136 + h1 * 448 + w1 * 8];
    xw[c * XW_STRIDE + p] = (val - bn_m[c]) * g + bn_b[c];
  }
  __syncthreads();

  // ---- 2) v[o][p] = sum_c Wv[o][c] * xw[c][p]; thread owns o = tid
  {
    float acc[HW];
#pragma unroll
    for (int p = 0; p < HW; ++p) acc[p] = 0.f;
#pragma unroll 2
    for (int c = 0; c < CIN; ++c) {
      float w = WvT[c * 256 + tid];
      const float4* xr4 = (const float4*)(xw + c * XW_STRIDE);
#pragma unroll
      for (int u = 0; u < 12; ++u) {
        float4 xv = xr4[u];
        acc[4 * u + 0] = fmaf(w, xv.x, acc[4 * u + 0]);
        acc[4 * u + 1] = fmaf(w, xv.y, acc[4 * u + 1]);
        acc[4 * u + 2] = fmaf(w, xv.z, acc[4 * u + 2]);
        acc[4 * u + 3] = fmaf(w, xv.w, acc[4 * u + 3]);
      }
      acc[48] = fmaf(w, xw[c * XW_STRIDE + 48], acc[48]);
    }
    float* vr = vv + tid * XW_STRIDE;
#pragma unroll
    for (int p = 0; p < HW; ++p) vr[p] = acc[p];
  }
  __syncthreads();

  const int d = tid & 63;
  const int i0 = tid >> 6;   // wave-uniform

  for (int h = 0; h < 4; ++h) {
    // ---- 3a) q,k for head h: thread owns (d, i = i0+4k)
    {
      float aq[13], ak[13];
#pragma unroll
      for (int k = 0; k < 13; ++k) { aq[k] = 0.f; ak[k] = 0.f; }
      const float* Wq = WqkT + h * 64 + d;
      const float* Wk = Wq + 256;
#pragma unroll 4
      for (int c = 0; c < CIN; ++c) {
        float wq = Wq[(size_t)c * 512];
        float wk = Wk[(size_t)c * 512];
        const float* xr = xw + c * XW_STRIDE + i0;
#pragma unroll
        for (int k = 0; k < 13; ++k) {
          if (i0 + 4 * k < HW) {
            float xv = xr[4 * k];
            aq[k] = fmaf(wq, xv, aq[k]);
            ak[k] = fmaf(wk, xv, ak[k]);
          }
        }
      }
#pragma unroll
      for (int k = 0; k < 13; ++k) {
        int i = i0 + 4 * k;
        if (i < HW) {
          qh[i * QK_STRIDE + d] = aq[k] * 0.125f;  // scale = 1/sqrt(64)
          kh[i * QK_STRIDE + d] = ak[k];
        }
      }
    }
    __syncthreads();

    // ---- 3b) scores S[i][j] = q[i]·k[j]
    for (int l = tid; l < HW * HW; l += 256) {
      int i = l / HW;
      int j = l - i * HW;
      const float4* qr = (const float4*)(qh + i * QK_STRIDE);
      const float4* kr = (const float4*)(kh + j * QK_STRIDE);
      float acc = 0.f;
#pragma unroll
      for (int t = 0; t < 16; ++t) {
        float4 a = qr[t], b = kr[t];
        acc += a.x * b.x + a.y * b.y + a.z * b.z + a.w * b.w;
      }
      Ss[i * XW_STRIDE + j] = acc;
    }
    __syncthreads();

    // ---- 3c) softmax per row
    if (tid < HW) {
      float* row = Ss + tid * XW_STRIDE;
      float m = -1e30f;
#pragma unroll
      for (int j = 0; j < HW; ++j) m = fmaxf(m, row[j]);
      float s = 0.f;
#pragma unroll
      for (int j = 0; j < HW; ++j) { float e = __expf(row[j] - m); row[j] = e; s += e; }
      float inv = 1.0f / s;
#pragma unroll
      for (int j = 0; j < HW; ++j) row[j] *= inv;
    }
    __syncthreads();

    // ---- 3d) PV + depthwise convs + fusion + store
    for (int l = tid; l < 64 * HW; l += 256) {
      int dd = l / HW;
      int p = l - dd * HW;
      int c = h * 64 + dd;
      const float* Sr = Ss + p * XW_STRIDE;
      const float* vr = vv + c * XW_STRIDE;
      // PV: x_spa[c][p] = sum_j S[p][j] * v[c][j]
      float spa = 0.f;
      {
        const float4* S4 = (const float4*)Sr;
        const float4* V4 = (const float4*)vr;
#pragma unroll
        for (int u = 0; u < 12; ++u) {
          float4 a = S4[u], b = V4[u];
          spa += a.x * b.x + a.y * b.y + a.z * b.z + a.w * b.w;
        }
        spa += Sr[48] * vr[48];
      }
      int h1 = p / 7, w1 = p - (p / 7) * 7;
      float s3 = 0.f;
      {
        const float* wp = w3 + c * 9;
#pragma unroll
        for (int dy = -1; dy <= 1; ++dy) {
          int hh = h1 + dy;
          if ((unsigned)hh < 7u) {
#pragma unroll
            for (int dx = -1; dx <= 1; ++dx) {
              int ww2 = w1 + dx;
              if ((unsigned)ww2 < 7u)
                s3 = fmaf(wp[(dy + 1) * 3 + (dx + 1)], vr[hh * 7 + ww2], s3);
            }
          }
        }
      }
      float s5 = 0.f;
      {
        const float* wp = w5 + c * 25;
#pragma unroll
        for (int dy = -2; dy <= 2; ++dy) {
          int hh = h1 + dy;
          if ((unsigned)hh < 7u) {
#pragma unroll
            for (int dx = -2; dx <= 2; ++dx) {
              int ww2 = w1 + dx;
              if ((unsigned)ww2 < 7u)
                s5 = fmaf(wp[(dy + 2) * 5 + (dx + 2)], vr[hh * 7 + ww2], s5);
            }
          }
        }
      }
      float s7 = 0.f;
      {
        const float* wp = w7 + c * 49;
#pragma unroll
        for (int dy = -3; dy <= 3; ++dy) {
          int hh = h1 + dy;
          if ((unsigned)hh < 7u) {
#pragma unroll
            for (int dx = -3; dx <= 3; ++dx) {
              int ww2 = w1 + dx;
              if ((unsigned)ww2 < 7u)
                s7 = fmaf(wp[(dy + 3) * 7 + (dx + 3)], vr[hh * 7 + ww2], s7);
            }
          }
        }
      }
      float outv = fmaf(spa, aw[c],
                   fmaf(s3, c3w[c],
                   fmaf(s5, c5w[c],
                   fmaf(s7, c7w[c], vr[p]))));
      xc_g[(size_t)win * (CIN * HW) + c * HW + p] = outv;
    }
    __syncthreads();
  }
}

__global__ __launch_bounds__(256) void proj_out(
    const float* __restrict__ x,
    const float* __restrict__ WprojT,
    const float* __restrict__ xc_g,
    float* __restrict__ out)
{
  __shared__ float xcs[256 * XW_STRIDE];
  const int win = blockIdx.x;
  const int bb = win >> 6, i1 = (win >> 3) & 7, i2 = win & 7;
  const int tid = threadIdx.x;

  const float* src = xc_g + (size_t)win * (CIN * HW);
  for (int t = tid; t < CIN * HW; t += 256) {
    int c = t / HW;
    int p = t - c * HW;
    xcs[c * XW_STRIDE + p] = src[t];
  }
  __syncthreads();

  float acc[HW];
#pragma unroll
  for (int p = 0; p < HW; ++p) acc[p] = 0.f;
#pragma unroll 2
  for (int c = 0; c < CIN; ++c) {
    float w = WprojT[c * 256 + tid];
    const float4* xr4 = (const float4*)(xcs + c * XW_STRIDE);
#pragma unroll
    for (int u = 0; u < 12; ++u) {
      float4 xv = xr4[u];
      acc[4 * u + 0] = fmaf(w, xv.x, acc[4 * u + 0]);
      acc[4 * u + 1] = fmaf(w, xv.y, acc[4 * u + 1]);
      acc[4 * u + 2] = fmaf(w, xv.z, acc[4 * u + 2]);
      acc[4 * u + 3] = fmaf(w, xv.w, acc[4 * u + 3]);
    }
    acc[48] = fmaf(w, xcs[c * XW_STRIDE + 48], acc[48]);
  }

  const size_t base = (size_t)bb * CIN * 3136 + (size_t)tid * 3136 + i1 * 56 + i2;
  const float* xb = x + base;
  float* ob = out + base;
#pragma unroll
  for (int p = 0; p < HW; ++p) {
    int h1 = p / 7, w1 = p - (p / 7) * 7;
    int off = h1 * 448 + w1 * 8;
    ob[off] = xb[off] + acc[p];
  }
}

extern "C" void kernel_launch(void* const* d_in, const int* in_sizes, int n_in,
                              void* d_out, int out_size, void* d_ws, size_t ws_size,
                              hipStream_t stream) {
  const float* x    = (const float*)d_in[0];
  const float* bn_g = (const float*)d_in[1];
  const float* bn_b = (const float*)d_in[2];
  const float* bn_m = (const float*)d_in[3];
  const float* bn_v = (const float*)d_in[4];
  const float* w_qk = (const float*)d_in[5];
  const float* w_v  = (const float*)d_in[6];
  const float* w3   = (const float*)d_in[7];
  const float* w5   = (const float*)d_in[8];
  const float* w7   = (const float*)d_in[9];
  const float* aw   = (const float*)d_in[10];
  const float* c3w  = (const float*)d_in[11];
  const float* c5w  = (const float*)d_in[12];
  const float* c7w  = (const float*)d_in[13];
  const float* w_pr = (const float*)d_in[14];
  float* out = (float*)d_out;
  float* ws = (float*)d_ws;

  float* WqkT   = ws;
  float* WvT    = ws + 131072;
  float* WprojT = ws + 196608;
  float* xc     = ws + 262144;

  transpose256<<<512, 256, 0, stream>>>(w_qk, WqkT, 512);
  transpose256<<<256, 256, 0, stream>>>(w_v, WvT, 256);
  transpose256<<<256, 256, 0, stream>>>(w_pr, WprojT, 256);

  const int smem_bytes = (256 * XW_STRIDE * 2 + HW * QK_STRIDE * 2 + HW * XW_STRIDE) * 4;
  hipFuncSetAttribute(reinterpret_cast<const void*>(win_attn),
                      hipFuncAttributeMaxDynamicSharedMemorySize, smem_bytes);

  win_attn<<<2048, 256, smem_bytes, stream>>>(
      x, bn_g, bn_b, bn_m, bn_v, WqkT, WvT, w3, w5, w7,
      aw, c3w, c5w, c7w, xc);

  proj_out<<<2048, 256, 0, stream>>>(x, WprojT, xc, out);
}

// Round 2
// 418.730 us; speedup vs baseline: 17.1331x; 17.1331x over previous
//
#include <hip/hip_runtime.h>
#include <cstddef>
#include <cstdint>

typedef short bf16x8 __attribute__((ext_vector_type(8)));
typedef float f32x4 __attribute__((ext_vector_type(4)));

#define MFMA16(a, b, c) __builtin_amdgcn_mfma_f32_16x16x32_bf16((a), (b), (c), 0, 0, 0)

__device__ __forceinline__ unsigned short f2bf(float f) {
  unsigned u = __float_as_uint(f);
  u = (u + 0x7FFFu + ((u >> 16) & 1u)) >> 16;
  return (unsigned short)u;
}
__device__ __forceinline__ float bf2f(unsigned short h) {
  return __uint_as_float(((unsigned)h) << 16);
}

// ---------------------------------------------------------------------------
// Weight prep: fold BN into Wqk/Wv (bf16) + f32 bias; cast Wproj; transpose dw
// weights to [k][c] for coalesced lane-c loads.
// ---------------------------------------------------------------------------
__global__ void wprep(const float* __restrict__ bn_g, const float* __restrict__ bn_b,
                      const float* __restrict__ bn_m, const float* __restrict__ bn_v,
                      const float* __restrict__ w_qk, const float* __restrict__ w_v,
                      const float* __restrict__ w_proj,
                      const float* __restrict__ w3, const float* __restrict__ w5,
                      const float* __restrict__ w7,
                      unsigned short* __restrict__ Wqk, unsigned short* __restrict__ Wv,
                      unsigned short* __restrict__ Wp,
                      float* __restrict__ bqk, float* __restrict__ bv,
                      float* __restrict__ w3T, float* __restrict__ w5T,
                      float* __restrict__ w7T) {
  int blk = blockIdx.x, t = threadIdx.x;
  if (blk == 4) {
    for (int idx = t; idx < 21248; idx += 256) {
      if (idx < 2304) {
        int k2 = idx >> 8, c = idx & 255;
        w3T[idx] = w3[c * 9 + k2];
      } else if (idx < 8704) {
        int i = idx - 2304;
        int k2 = i >> 8, c = i & 255;
        w5T[i] = w5[c * 25 + k2];
      } else {
        int i = idx - 8704;
        int k2 = i >> 8, c = i & 255;
        w7T[i] = w7[c * 49 + k2];
      }
    }
    return;
  }
  int o = blk * 256 + t;  // 0..1023
  if (o < 512) {
    float scale = (o < 256) ? 0.125f : 1.0f;  // q rows get 1/sqrt(64)
    float bias = 0.f;
    for (int c = 0; c < 256; ++c) {
      float g = bn_g[c] / sqrtf(bn_v[c] + 1e-5f);
      float be = bn_b[c] - bn_m[c] * g;
      float wv = w_qk[o * 256 + c];
      bias += wv * be;
      Wqk[o * 256 + c] = f2bf(wv * g * scale);
    }
    bqk[o] = bias * scale;
  } else if (o < 768) {
    int oo = o - 512;
    float bias = 0.f;
    for (int c = 0; c < 256; ++c) {
      float g = bn_g[c] / sqrtf(bn_v[c] + 1e-5f);
      float be = bn_b[c] - bn_m[c] * g;
      float wv = w_v[oo * 256 + c];
      bias += wv * be;
      Wv[oo * 256 + c] = f2bf(wv * g);
    }
    bv[oo] = bias;
  } else {
    int oo = o - 768;
    for (int c = 0; c < 256; ++c) Wp[oo * 256 + c] = f2bf(w_proj[oo * 256 + c]);
  }
}

// ---------------------------------------------------------------------------
// Transpose+cast: x f32 [32][256][3136] -> xT bf16 [pix=32*3136][256]
// ---------------------------------------------------------------------------
__global__ __launch_bounds__(256) void xpose(const float* __restrict__ x,
                                             unsigned short* __restrict__ xT) {
  __shared__ float tile[64 * 68];  // stride 68 for alignment + bank spread
  int blk = blockIdx.x;
  int bb = blk / 196;
  int rem = blk - bb * 196;
  int cblk = rem / 49;
  int pblk = rem - cblk * 49;
  int t = threadIdx.x;
  {
    int r = t >> 2, seg = t & 3;
    const float* src = x + (size_t)bb * 802816 + (size_t)(cblk * 64 + r) * 3136 +
                       pblk * 64 + seg * 16;
    float4 v0 = ((const float4*)src)[0];
    float4 v1 = ((const float4*)src)[1];
    float4 v2 = ((const float4*)src)[2];
    float4 v3 = ((const float4*)src)[3];
    float* td = tile + r * 68 + seg * 16;
    td[0] = v0.x; td[1] = v0.y; td[2] = v0.z; td[3] = v0.w;
    td[4] = v1.x; td[5] = v1.y; td[6] = v1.z; td[7] = v1.w;
    td[8] = v2.x; td[9] = v2.y; td[10] = v2.z; td[11] = v2.w;
    td[12] = v3.x; td[13] = v3.y; td[14] = v3.z; td[15] = v3.w;
  }
  __syncthreads();
  {
    int p = t >> 2, cs = t & 3;
    alignas(16) unsigned short tmp[16];
#pragma unroll
    for (int u = 0; u < 16; ++u) tmp[u] = f2bf(tile[(cs * 16 + u) * 68 + p]);
    unsigned short* dst = xT + (size_t)(bb * 3136 + pblk * 64 + p) * 256 +
                          cblk * 64 + cs * 16;
    ((uint4*)dst)[0] = *(const uint4*)(tmp);
    ((uint4*)dst)[1] = *(const uint4*)(tmp + 8);
  }
}

// ---------------------------------------------------------------------------
// Fused per-window: v GEMM, per-head qk GEMM -> S -> softmax -> PV,
// depthwise 3/5/7 + fusion -> xcT bf16 [pix][256]
// LDS layout (bytes):
//   v_lds [256][72]  : 0      .. 36864
//   xw    [49][264]  : 36864  .. 62736
//   q_lds [2][64][72]: 62736  .. 81168
//   k_lds [2][64][72]: 81168  .. 99600
//   Sb    [2][64][72]: 99600  .. 118032
//   spa   [2][64][52]: 118032 .. 144656   (f32)
// ---------------------------------------------------------------------------
__global__ __launch_bounds__(512, 2) void k2_win(
    const unsigned short* __restrict__ xT, const unsigned short* __restrict__ Wqk,
    const unsigned short* __restrict__ Wv, const float* __restrict__ bqk,
    const float* __restrict__ bv, const float* __restrict__ w3T,
    const float* __restrict__ w5T, const float* __restrict__ w7T,
    const float* __restrict__ aw, const float* __restrict__ c3w,
    const float* __restrict__ c5w, const float* __restrict__ c7w,
    unsigned short* __restrict__ xcT) {
  extern __shared__ char smem[];
  unsigned short* v_lds = (unsigned short*)smem;             // [256][72]
  unsigned short* xw = (unsigned short*)(smem + 36864);      // [49][264]
  unsigned short* q_lds = (unsigned short*)(smem + 62736);   // [2][64][72]
  unsigned short* k_lds = (unsigned short*)(smem + 81168);   // [2][64][72]
  unsigned short* Sb = (unsigned short*)(smem + 99600);      // [2][64][72]
  float* spa = (float*)(smem + 118032);                      // [2][64][52]

  const int tid = threadIdx.x;
  const int l = tid & 63;
  const int w = tid >> 6;  // wave id 0..7
  const int l15 = l & 15;
  const int lg = l >> 4;
  const int blk = blockIdx.x;
  const int bb = blk >> 6, i1 = (blk >> 3) & 7, i2 = blk & 7;

  // ---- Phase A: gather window rows of xT into LDS [p][c]
  for (int idx = tid; idx < 1568; idx += 512) {
    int r = idx >> 5, seg = idx & 31;
    int h1 = (r * 9363) >> 16;  // r/7 for r<64
    int w1 = r - h1 * 7;
    int pix = bb * 3136 + (h1 * 8 + i1) * 56 + w1 * 8 + i2;
    uint4 d = *(const uint4*)(xT + (size_t)pix * 256 + seg * 8);
    *(uint4*)(xw + r * 264 + seg * 8) = d;
  }
  __syncthreads();

  // ---- Phase B: v GEMM (M=256 cmid, N=64 p padded, K=256)
  {
    f32x4 acc[2][4];
#pragma unroll
    for (int mf = 0; mf < 2; ++mf)
#pragma unroll
      for (int nt = 0; nt < 4; ++nt) acc[mf][nt] = (f32x4){0.f, 0.f, 0.f, 0.f};
#pragma unroll 2
    for (int ks = 0; ks < 8; ++ks) {
      bf16x8 a0 = *(const bf16x8*)(Wv + (w * 32 + l15) * 256 + ks * 32 + lg * 8);
      bf16x8 a1 = *(const bf16x8*)(Wv + (w * 32 + 16 + l15) * 256 + ks * 32 + lg * 8);
      bf16x8 b[4];
#pragma unroll
      for (int nt = 0; nt < 4; ++nt) {
        int j = nt * 16 + l15;
        if (j > 48) j = 48;
        b[nt] = *(const bf16x8*)(xw + j * 264 + ks * 32 + lg * 8);
      }
#pragma unroll
      for (int nt = 0; nt < 4; ++nt) {
        acc[0][nt] = MFMA16(a0, b[nt], acc[0][nt]);
        acc[1][nt] = MFMA16(a1, b[nt], acc[1][nt]);
      }
    }
#pragma unroll
    for (int mf = 0; mf < 2; ++mf)
#pragma unroll
      for (int ri = 0; ri < 4; ++ri) {
        int c = w * 32 + mf * 16 + lg * 4 + ri;
        float bvv = bv[c];
#pragma unroll
        for (int nt = 0; nt < 4; ++nt) {
          int p = nt * 16 + l15;
          v_lds[c * 72 + p] = f2bf(acc[mf][nt][ri] + bvv);
        }
      }
  }
  __syncthreads();

  // ---- head pairs
  for (int hp = 0; hp < 2; ++hp) {
    const int hs = w >> 2;   // head slot within pair
    const int sub = w & 3;   // sub-role
    const int h = hp * 2 + hs;

    // C1: qk GEMM for head h (q: sub 0,1 ; k: sub 2,3), write transposed to LDS
    {
      int obase = (sub < 2) ? (h * 64 + sub * 32) : (256 + h * 64 + (sub & 1) * 32);
      f32x4 acc[2][4];
#pragma unroll
      for (int mf = 0; mf < 2; ++mf)
#pragma unroll
        for (int nt = 0; nt < 4; ++nt) acc[mf][nt] = (f32x4){0.f, 0.f, 0.f, 0.f};
#pragma unroll 2
      for (int ks = 0; ks < 8; ++ks) {
        bf16x8 a0 = *(const bf16x8*)(Wqk + (obase + l15) * 256 + ks * 32 + lg * 8);
        bf16x8 a1 = *(const bf16x8*)(Wqk + (obase + 16 + l15) * 256 + ks * 32 + lg * 8);
        bf16x8 b[4];
#pragma unroll
        for (int nt = 0; nt < 4; ++nt) {
          int j = nt * 16 + l15;
          if (j > 48) j = 48;
          b[nt] = *(const bf16x8*)(xw + j * 264 + ks * 32 + lg * 8);
        }
#pragma unroll
        for (int nt = 0; nt < 4; ++nt) {
          acc[0][nt] = MFMA16(a0, b[nt], acc[0][nt]);
          acc[1][nt] = MFMA16(a1, b[nt], acc[1][nt]);
        }
      }
      unsigned short* dst = ((sub < 2) ? q_lds : k_lds) + hs * 4608;
      int dbase = (sub & 1) * 32;
#pragma unroll
      for (int mf = 0; mf < 2; ++mf)
#pragma unroll
        for (int ri = 0; ri < 4; ++ri) {
          float bias = bqk[obase + mf * 16 + lg * 4 + ri];
          int d = dbase + mf * 16 + lg * 4 + ri;
#pragma unroll
          for (int nt = 0; nt < 4; ++nt) {
            int p = nt * 16 + l15;
            dst[p * 72 + d] = f2bf(acc[mf][nt][ri] + bias);
          }
        }
    }
    __syncthreads();

    // C2: S = q k^T (wave = 16 i-rows), in-register softmax, Sb bf16
    {
      f32x4 s[4];
#pragma unroll
      for (int nt = 0; nt < 4; ++nt) s[nt] = (f32x4){0.f, 0.f, 0.f, 0.f};
#pragma unroll
      for (int ks = 0; ks < 2; ++ks) {
        bf16x8 a = *(const bf16x8*)(q_lds + hs * 4608 + (sub * 16 + l15) * 72 +
                                    ks * 32 + lg * 8);
        bf16x8 b[4];
#pragma unroll
        for (int nt = 0; nt < 4; ++nt)
          b[nt] = *(const bf16x8*)(k_lds + hs * 4608 + (nt * 16 + l15) * 72 +
                                   ks * 32 + lg * 8);
#pragma unroll
        for (int nt = 0; nt < 4; ++nt) s[nt] = MFMA16(a, b[nt], s[nt]);
      }
#pragma unroll
      for (int ri = 0; ri < 4; ++ri) {
        float s0 = s[0][ri], s1 = s[1][ri], s2 = s[2][ri], s3v = s[3][ri];
        if (l15 != 0) s3v = -1e30f;  // mask j = 49..63
        float m = fmaxf(fmaxf(s0, s1), fmaxf(s2, s3v));
        m = fmaxf(m, __shfl_xor(m, 1));
        m = fmaxf(m, __shfl_xor(m, 2));
        m = fmaxf(m, __shfl_xor(m, 4));
        m = fmaxf(m, __shfl_xor(m, 8));
        float e0 = __expf(s0 - m), e1 = __expf(s1 - m);
        float e2 = __expf(s2 - m), e3 = __expf(s3v - m);
        float sum = e0 + e1 + e2 + e3;
        sum += __shfl_xor(sum, 1);
        sum += __shfl_xor(sum, 2);
        sum += __shfl_xor(sum, 4);
        sum += __shfl_xor(sum, 8);
        float inv = 1.f / sum;
        int row = sub * 16 + lg * 4 + ri;
        unsigned short* sb = Sb + hs * 4608 + row * 72 + l15;
        sb[0] = f2bf(e0 * inv);
        sb[16] = f2bf(e1 * inv);
        sb[32] = f2bf(e2 * inv);
        sb[48] = f2bf(e3 * inv);
      }
    }
    __syncthreads();

    // C3: PV -> spa[hs][d'][p] f32
    {
      f32x4 acc[4];
#pragma unroll
      for (int nt = 0; nt < 4; ++nt) acc[nt] = (f32x4){0.f, 0.f, 0.f, 0.f};
#pragma unroll
      for (int ks = 0; ks < 2; ++ks) {
        bf16x8 a = *(const bf16x8*)(Sb + hs * 4608 + (sub * 16 + l15) * 72 +
                                    ks * 32 + lg * 8);
        bf16x8 b[4];
#pragma unroll
        for (int nt = 0; nt < 4; ++nt)
          b[nt] = *(const bf16x8*)(v_lds + (h * 64 + nt * 16 + l15) * 72 +
                                   ks * 32 + lg * 8);
#pragma unroll
        for (int nt = 0; nt < 4; ++nt) acc[nt] = MFMA16(a, b[nt], acc[nt]);
      }
#pragma unroll
      for (int nt = 0; nt < 4; ++nt)
#pragma unroll
        for (int ri = 0; ri < 4; ++ri) {
          int p = sub * 16 + lg * 4 + ri;
          if (p < 49) spa[hs * 3328 + (nt * 16 + l15) * 52 + p] = acc[nt][ri];
        }
    }
    __syncthreads();

    // C4: depthwise 3/5/7 + weighted fusion + residual, store xcT
    {
      int cl = ((w & 1) << 6) + l;  // 0..127
      int c = hp * 128 + cl;
      int hs2 = cl >> 6, dp = cl & 63;
      const float* spaC = spa + hs2 * 3328 + dp * 52;
      float awc = aw[c], c3c = c3w[c], c5c = c5w[c], c7c = c7w[c];
      float W3[9], W5[25], W7[49];
#pragma unroll
      for (int k2 = 0; k2 < 9; ++k2) W3[k2] = w3T[k2 * 256 + c];
#pragma unroll
      for (int k2 = 0; k2 < 25; ++k2) W5[k2] = w5T[k2 * 256 + c];
#pragma unroll
      for (int k2 = 0; k2 < 49; ++k2) W7[k2] = w7T[k2 * 256 + c];
#pragma unroll
      for (int pass = 0; pass < 2; ++pass) {
        int hr = (w >> 1) + pass * 4;  // wave-uniform window row
        if (hr <= 6) {
          float vr[7][7];
#pragma unroll
          for (int dy = -3; dy <= 3; ++dy) {
            int ry = hr + dy;
            if ((unsigned)ry < 7u) {
#pragma unroll
              for (int cc = 0; cc < 7; ++cc)
                vr[dy + 3][cc] = bf2f(v_lds[c * 72 + ry * 7 + cc]);
            }
          }
          float sp[7];
#pragma unroll
          for (int ww = 0; ww < 7; ++ww) sp[ww] = spaC[hr * 7 + ww];
#pragma unroll
          for (int ww = 0; ww < 7; ++ww) {
            float s3a = 0.f, s5a = 0.f, s7a = 0.f;
#pragma unroll
            for (int dy = -3; dy <= 3; ++dy) {
              if ((unsigned)(hr + dy) < 7u) {
#pragma unroll
                for (int dx = -3; dx <= 3; ++dx) {
                  int cc = ww + dx;
                  if (cc >= 0 && cc < 7) {
                    float vv = vr[dy + 3][cc];
                    s7a = fmaf(W7[(dy + 3) * 7 + dx + 3], vv, s7a);
                    if (dy >= -2 && dy <= 2 && dx >= -2 && dx <= 2)
                      s5a = fmaf(W5[(dy + 2) * 5 + dx + 2], vv, s5a);
                    if (dy >= -1 && dy <= 1 && dx >= -1 && dx <= 1)
                      s3a = fmaf(W3[(dy + 1) * 3 + dx + 1], vv, s3a);
                  }
                }
              }
            }
            float val = sp[ww] * awc + s3a * c3c + s5a * c5c + s7a * c7c + vr[3][ww];
            int pixp = bb * 3136 + (hr * 8 + i1) * 56 + ww * 8 + i2;
            xcT[(size_t)pixp * 256 + c] = f2bf(val);
          }
        }
      }
    }
    __syncthreads();
  }
}

// ---------------------------------------------------------------------------
// Proj GEMM (M=256, N=pix, K=256) + shortcut residual, f32 out
// ---------------------------------------------------------------------------
__global__ __launch_bounds__(256) void k3_proj(const unsigned short* __restrict__ Wp,
                                               const unsigned short* __restrict__ xcT,
                                               const float* __restrict__ x,
                                               float* __restrict__ out) {
  const int tid = threadIdx.x, l = tid & 63, w = tid >> 6;
  const int l15 = l & 15, lg = l >> 4;
  const int blk = blockIdx.x;
  f32x4 acc[4][4];
#pragma unroll
  for (int mf = 0; mf < 4; ++mf)
#pragma unroll
    for (int nf = 0; nf < 4; ++nf) acc[mf][nf] = (f32x4){0.f, 0.f, 0.f, 0.f};
#pragma unroll 2
  for (int ks = 0; ks < 8; ++ks) {
    bf16x8 a[4], b[4];
#pragma unroll
    for (int mf = 0; mf < 4; ++mf)
      a[mf] = *(const bf16x8*)(Wp + (w * 64 + mf * 16 + l15) * 256 + ks * 32 + lg * 8);
#pragma unroll
    for (int nf = 0; nf < 4; ++nf)
      b[nf] = *(const bf16x8*)(xcT + (size_t)(blk * 64 + nf * 16 + l15) * 256 +
                               ks * 32 + lg * 8);
#pragma unroll
    for (int mf = 0; mf < 4; ++mf)
#pragma unroll
      for (int nf = 0; nf < 4; ++nf) acc[mf][nf] = MFMA16(a[mf], b[nf], acc[mf][nf]);
  }
  int bb = (blk * 64) / 3136;
  int loc0 = blk * 64 - bb * 3136;
#pragma unroll
  for (int mf = 0; mf < 4; ++mf)
#pragma unroll
    for (int nf = 0; nf < 4; ++nf)
#pragma unroll
      for (int ri = 0; ri < 4; ++ri) {
        int o = w * 64 + mf * 16 + lg * 4 + ri;
        int ploc = loc0 + nf * 16 + l15;
        size_t addr = (size_t)bb * 802816 + (size_t)o * 3136 + ploc;
        out[addr] = x[addr] + acc[mf][nf][ri];
      }
}

// ---------------------------------------------------------------------------
extern "C" void kernel_launch(void* const* d_in, const int* in_sizes, int n_in,
                              void* d_out, int out_size, void* d_ws, size_t ws_size,
                              hipStream_t stream) {
  const float* x = (const float*)d_in[0];
  const float* bn_g = (const float*)d_in[1];
  const float* bn_b = (const float*)d_in[2];
  const float* bn_m = (const float*)d_in[3];
  const float* bn_v = (const float*)d_in[4];
  const float* w_qk = (const float*)d_in[5];
  const float* w_v = (const float*)d_in[6];
  const float* w3 = (const float*)d_in[7];
  const float* w5 = (const float*)d_in[8];
  const float* w7 = (const float*)d_in[9];
  const float* aw = (const float*)d_in[10];
  const float* c3w = (const float*)d_in[11];
  const float* c5w = (const float*)d_in[12];
  const float* c7w = (const float*)d_in[13];
  const float* w_pr = (const float*)d_in[14];
  float* out = (float*)d_out;
  char* ws = (char*)d_ws;

  unsigned short* Wqk = (unsigned short*)ws;                  // 512x256 bf16
  unsigned short* Wv = (unsigned short*)(ws + 262144);        // 256x256 bf16
  unsigned short* Wp = (unsigned short*)(ws + 393216);        // 256x256 bf16
  float* bqk = (float*)(ws + 524288);                         // 512 f32
  float* bv = (float*)(ws + 526336);                          // 256 f32
  float* w3T = (float*)(ws + 527360);                         // 9x256
  float* w5T = (float*)(ws + 536576);                         // 25x256
  float* w7T = (float*)(ws + 562176);                         // 49x256
  unsigned short* xT = (unsigned short*)(ws + 1048576);       // 100352x256 bf16
  unsigned short* xcT = (unsigned short*)(ws + 52428800);     // 100352x256 bf16

  wprep<<<5, 256, 0, stream>>>(bn_g, bn_b, bn_m, bn_v, w_qk, w_v, w_pr, w3, w5, w7,
                               Wqk, Wv, Wp, bqk, bv, w3T, w5T, w7T);
  xpose<<<6272, 256, 0, stream>>>(x, xT);
  hipFuncSetAttribute(reinterpret_cast<const void*>(k2_win),
                      hipFuncAttributeMaxDynamicSharedMemorySize, 144656);
  k2_win<<<2048, 512, 144656, stream>>>(xT, Wqk, Wv, bqk, bv, w3T, w5T, w7T, aw, c3w,
                                        c5w, c7w, xcT);
  k3_proj<<<1568, 256, 0, stream>>>(Wp, xcT, x, out);
}